// Round 8
// baseline (172.733 us; speedup 1.0000x reference)
//
#include <hip/hip_runtime.h>

// Problem constants
#define BINS 500
#define HID  512
#define INDD 128
#define PAIR_S 0.044194173824159216f   // 1/sqrt(512)

// d_out float offsets (outputs concatenated flat: out_mc, out_ih, micro, out_hic)
#define OFF_MC    0
#define OFF_IH    320000
#define OFF_MICRO 640000
#define OFF_HIC   32640000

// ws float offsets.
// [0..256000) holds H1 (gemm1 partial sums, dead after gemm2), then reused:
//   U at 0 (500x128 f32), MWT at 64000 (bf16[128][512] = s*micro_w^T),
//   HBF at 96768 (bf16[500][512] = h+b2)
#define WS_U     0
#define WS_MWT   64000
#define WS_HBF   96768
#define WS_H     256000    // 500*512 f32 (h partial sums, no bias)
#define WS_HBAR  512000    // 100*512 f32 (pooled h+b2)
#define WS_HWT   563200    // bf16[128][512]  (hic_w^T)
#define WS_W1CT  595968    // bf16[80][128]   (head_ih_w1 | head_mc_w, transposed)

typedef __bf16 bf16;
typedef bf16 bf16x4 __attribute__((ext_vector_type(4)));
typedef bf16 bf16x8 __attribute__((ext_vector_type(8)));
typedef float f32x4 __attribute__((ext_vector_type(4)));

__device__ __forceinline__ bf16x8 join8(bf16x4 lo, bf16x4 hi) {
  return __builtin_shufflevector(lo, hi, 0, 1, 2, 3, 4, 5, 6, 7);
}
__device__ __forceinline__ bf16x4 cvt4(float a, float b, float c, float d) {
  bf16x4 r; r[0] = (bf16)a; r[1] = (bf16)b; r[2] = (bf16)c; r[3] = (bf16)d; return r;
}

// ---------------------------------------------------------------------------
// zero_init: zero H1 and H accumulators (proper grid, float4 stores).
// ---------------------------------------------------------------------------
__global__ void zero_init(float* __restrict__ ws) {
  int idx = (blockIdx.x * 256 + threadIdx.x) * 4;
  float4 z = {0.f, 0.f, 0.f, 0.f};
  *(float4*)(ws + idx) = z;            // H1
  *(float4*)(ws + WS_H + idx) = z;     // H
}

// ---------------------------------------------------------------------------
// Split-K GEMM: C += scale * (opA(A) @ B), opA = relu(a + abias) | (a + abias) | a.
// blockIdx.z = K-slice; epilogue atomicAdd. C must be zeroed before launch.
// ---------------------------------------------------------------------------
__global__ __launch_bounds__(256, 2)
void gemm_ks(const float* __restrict__ A, const float* __restrict__ B,
             const float* __restrict__ abias, float* __restrict__ C,
             int M, int N, int K_per, int a_relu, float scale) {
  __shared__ float a_lds[64][36];
  __shared__ float bt_lds[64][36];
  const int t = threadIdx.x;
  const int w = t >> 6, l = t & 63;
  const int lr = l & 15, g = l >> 4;
  const int r0 = blockIdx.x * 64, n0 = blockIdx.y * 64;
  const int kbase = blockIdx.z * K_per;
  f32x4 acc[4] = {};
  for (int kq = 0; kq < K_per; kq += 32) {
    const int k0 = kbase + kq;
    { // stage A rows (+ optional bias/relu)
      int row = t >> 2, kc = (t & 3) * 8;
      int gr = r0 + row; gr = gr < M ? gr : M - 1;
      const float* src = A + (size_t)gr * K_per * gridDim.z + k0 + kc;
      float4 v0 = *(const float4*)src;
      float4 v1 = *(const float4*)(src + 4);
      if (abias) {
        const float* bp = abias + k0 + kc;
        v0.x += bp[0]; v0.y += bp[1]; v0.z += bp[2]; v0.w += bp[3];
        v1.x += bp[4]; v1.y += bp[5]; v1.z += bp[6]; v1.w += bp[7];
        if (a_relu) {
          v0.x = fmaxf(v0.x, 0.f); v0.y = fmaxf(v0.y, 0.f);
          v0.z = fmaxf(v0.z, 0.f); v0.w = fmaxf(v0.w, 0.f);
          v1.x = fmaxf(v1.x, 0.f); v1.y = fmaxf(v1.y, 0.f);
          v1.z = fmaxf(v1.z, 0.f); v1.w = fmaxf(v1.w, 0.f);
        }
      }
      *(float4*)&a_lds[row][kc]     = v0;
      *(float4*)&a_lds[row][kc + 4] = v1;
    }
    { // stage B^T (coalesced across lanes)
      int n = t & 63, ks = (t >> 6) * 8;
      const float* src = B + (size_t)(k0 + ks) * N + n0 + n;
      #pragma unroll
      for (int s = 0; s < 8; s++) bt_lds[n][ks + s] = src[(size_t)s * N];
    }
    __syncthreads();
    bf16x8 ahi, alo;
    {
      int row = w * 16 + lr;
      float4 u0 = *(const float4*)&a_lds[row][g * 8];
      float4 u1 = *(const float4*)&a_lds[row][g * 8 + 4];
      float v[8] = {u0.x, u0.y, u0.z, u0.w, u1.x, u1.y, u1.z, u1.w};
      #pragma unroll
      for (int e = 0; e < 8; e++) {
        bf16 h = (bf16)v[e];
        ahi[e] = h; alo[e] = (bf16)(v[e] - (float)h);
      }
    }
    #pragma unroll
    for (int fn = 0; fn < 4; fn++) {
      int col = fn * 16 + lr;
      float4 u0 = *(const float4*)&bt_lds[col][g * 8];
      float4 u1 = *(const float4*)&bt_lds[col][g * 8 + 4];
      float v[8] = {u0.x, u0.y, u0.z, u0.w, u1.x, u1.y, u1.z, u1.w};
      bf16x8 bhi, blo;
      #pragma unroll
      for (int e = 0; e < 8; e++) {
        bf16 h = (bf16)v[e];
        bhi[e] = h; blo[e] = (bf16)(v[e] - (float)h);
      }
      acc[fn] = __builtin_amdgcn_mfma_f32_16x16x32_bf16(ahi, bhi, acc[fn], 0, 0, 0);
      acc[fn] = __builtin_amdgcn_mfma_f32_16x16x32_bf16(ahi, blo, acc[fn], 0, 0, 0);
      acc[fn] = __builtin_amdgcn_mfma_f32_16x16x32_bf16(alo, bhi, acc[fn], 0, 0, 0);
    }
    __syncthreads();
  }
  #pragma unroll
  for (int fn = 0; fn < 4; fn++) {
    int col = n0 + fn * 16 + lr;
    #pragma unroll
    for (int r = 0; r < 4; r++) {
      int row = r0 + w * 16 + g * 4 + r;
      if (row < M) atomicAdd(&C[(size_t)row * N + col], acc[fn][r] * scale);
    }
  }
}

// ---------------------------------------------------------------------------
// post_h: HBF = bf16(h+b2), MWT = bf16(s*micro_w^T), hbar pool (of h+b2),
// hwt/w1c weight prep, and zero the U accumulator (H1 region now dead).
// ---------------------------------------------------------------------------
__global__ void post_h(const float* __restrict__ h, const float* __restrict__ b2,
                       const float* __restrict__ micro_w,
                       const float* __restrict__ hic_w, const float* __restrict__ w_ih1,
                       const float* __restrict__ w_mc, float* __restrict__ ws) {
  int g = blockIdx.x * 256 + threadIdx.x;
  if (g < 256000) {
    bf16* hbf = (bf16*)(ws + WS_HBF);
    int k = g & (HID - 1);
    hbf[g] = (bf16)(h[g] + b2[k]);
  } else if (g < 256000 + 65536) {
    int gg = g - 256000;
    int n = gg >> 9, k = gg & 511;
    bf16* mwt = (bf16*)(ws + WS_MWT);
    mwt[gg] = (bf16)(PAIR_S * micro_w[k * INDD + n]);
  } else if (g < 256000 + 65536 + 51200) {
    int gg = g - (256000 + 65536);
    int a = gg >> 9, k = gg & (HID - 1);
    const float* p = h + (size_t)(a * 5) * HID + k;
    ws[WS_HBAR + gg] = 0.2f * (p[0] + p[HID] + p[2 * HID] + p[3 * HID] + p[4 * HID]) + b2[k];
  } else if (g < 256000 + 65536 + 51200 + 65536) {
    int gg = g - (256000 + 65536 + 51200);
    int n = gg >> 9, k = gg & 511;
    bf16* hwt = (bf16*)(ws + WS_HWT);
    hwt[gg] = (bf16)hic_w[k * INDD + n];
  } else if (g < 256000 + 65536 + 51200 + 65536 + 10240) {
    int gg = g - (256000 + 65536 + 51200 + 65536);
    int n = gg >> 7, k = gg & 127;
    float v = 0.f;
    if (n < 64) v = w_ih1[k * 64 + n];
    else if (n < 66) v = w_mc[k * 2 + (n - 64)];
    bf16* w1c = (bf16*)(ws + WS_W1CT);
    w1c[gg] = (bf16)v;
  } else if (g < 256000 + 65536 + 51200 + 65536 + 10240 + 64000) {
    int gg = g - (256000 + 65536 + 51200 + 65536 + 10240);
    ws[WS_U + gg] = 0.f;               // zero U accumulator
  }
}

// ---------------------------------------------------------------------------
// fused micro + heads. Block = 128j x 128n (i fixed), 4 waves, BK=32 dbuf,
// counted vmcnt, inline B'-gen (HBF[i]*MWT in regs). Epilogue 1 writes the
// f32 micro tile to global; epilogue 2 reads it straight back (own tile =
// L2-hot, row-major in n so A-fragments need NO transpose), converts to bf16
// (bit-identical to the old heads_kernel) and runs the mc+ih heads.
// ---------------------------------------------------------------------------
__global__ __launch_bounds__(256, 3)
void fused_micro_heads(const float* __restrict__ wsf, const float* __restrict__ micro_b,
                       const float* __restrict__ b1, const float* __restrict__ w2,
                       const float* __restrict__ bmc, const float* __restrict__ b2,
                       float* __restrict__ out) {
  __shared__ bf16 smem[16384];   // Ht dbuf [0,8192) + Bt dbuf [8192,16384)
  const int t = threadIdx.x;
  const int wv = t >> 6, l = t & 63;
  const int wj = wv >> 1, wn = wv & 1;
  const int lr = l & 15, g = l >> 4;
  const int i  = blockIdx.x;
  const int j0 = blockIdx.y * 128;
  const bf16* Hbf = (const bf16*)(wsf + WS_HBF);
  const bf16* mwt = (const bf16*)(wsf + WS_MWT);
  const float* U  = wsf + WS_U;
  const int bn = t >> 1, bh = t & 1;            // B'-gen: n-row, k-half(16)
  const int arow   = l >> 2;                    // A-stage: row within 16-group
  const int achunk = (l & 3) ^ ((l >> 3) & 3);  // pre-swizzled source 16B chunk
  const bf16* hbi = Hbf + (size_t)i * HID;
  f32x4 acc[4][4] = {};

  // ---- prologue: tile 0 ----
  #pragma unroll
  for (int q = 0; q < 2; q++) {
    int row = wv * 32 + q * 16 + arow;
    int jj = j0 + row; jj = jj < BINS ? jj : BINS - 1;
    __builtin_amdgcn_global_load_lds(
        (const __attribute__((address_space(1))) void*)(Hbf + (size_t)jj * HID + achunk * 8),
        (__attribute__((address_space(3))) void*)(smem + (wv * 32 + q * 16) * 32),
        16, 0, 0);
  }
  {
    bf16x8 w0 = *(const bf16x8*)(mwt + (size_t)bn * HID + bh * 16);
    bf16x8 w1 = *(const bf16x8*)(mwt + (size_t)bn * HID + bh * 16 + 8);
    bf16x8 h0 = *(const bf16x8*)(hbi + bh * 16);
    bf16x8 h1 = *(const bf16x8*)(hbi + bh * 16 + 8);
    bf16x8 o0, o1;
    #pragma unroll
    for (int e = 0; e < 8; e++) o0[e] = (bf16)((float)h0[e] * (float)w0[e]);
    #pragma unroll
    for (int e = 0; e < 8; e++) o1[e] = (bf16)((float)h1[e] * (float)w1[e]);
    const int sw = (bn >> 1) & 3;
    *(bf16x8*)(smem + 8192 + bn * 32 + ((bh * 2)     ^ sw) * 8) = o0;
    *(bf16x8*)(smem + 8192 + bn * 32 + ((bh * 2 + 1) ^ sw) * 8) = o1;
  }
  asm volatile("s_waitcnt vmcnt(0) lgkmcnt(0)" ::: "memory");
  __builtin_amdgcn_s_barrier();

  // ---- main loop: 16 K-steps of 32 ----
  int cur = 0;
  for (int kt = 0; kt < 16; kt++) {
    const bf16* htc = smem + cur * 4096;
    const bf16* btc = smem + 8192 + cur * 4096;
    bf16x8 w0, w1, h0, h1;
    if (kt < 15) {
      const int kn = (kt + 1) * 32;
      w0 = *(const bf16x8*)(mwt + (size_t)bn * HID + kn + bh * 16);
      w1 = *(const bf16x8*)(mwt + (size_t)bn * HID + kn + bh * 16 + 8);
      h0 = *(const bf16x8*)(hbi + kn + bh * 16);
      h1 = *(const bf16x8*)(hbi + kn + bh * 16 + 8);
      #pragma unroll
      for (int q = 0; q < 2; q++) {
        int row = wv * 32 + q * 16 + arow;
        int jj = j0 + row; jj = jj < BINS ? jj : BINS - 1;
        __builtin_amdgcn_global_load_lds(
            (const __attribute__((address_space(1))) void*)(Hbf + (size_t)jj * HID + kn + achunk * 8),
            (__attribute__((address_space(3))) void*)(smem + (cur ^ 1) * 4096 + (wv * 32 + q * 16) * 32),
            16, 0, 0);
      }
      asm volatile("s_waitcnt vmcnt(6)" ::: "memory");
    } else {
      asm volatile("s_waitcnt vmcnt(0)" ::: "memory");
    }
    bf16x8 af[4], bfr[4];
    const int s = g ^ ((lr >> 1) & 3);
    #pragma unroll
    for (int fm = 0; fm < 4; fm++)
      af[fm] = *(const bf16x8*)(htc + (wj * 64 + fm * 16 + lr) * 32 + s * 8);
    #pragma unroll
    for (int fn = 0; fn < 4; fn++)
      bfr[fn] = *(const bf16x8*)(btc + (wn * 64 + fn * 16 + lr) * 32 + s * 8);
    #pragma unroll
    for (int fm = 0; fm < 4; fm++)
      #pragma unroll
      for (int fn = 0; fn < 4; fn++)
        acc[fm][fn] = __builtin_amdgcn_mfma_f32_16x16x32_bf16(af[fm], bfr[fn], acc[fm][fn], 0, 0, 0);
    if (kt < 15) {
      bf16x8 o0, o1;
      #pragma unroll
      for (int e = 0; e < 8; e++) o0[e] = (bf16)((float)h0[e] * (float)w0[e]);
      #pragma unroll
      for (int e = 0; e < 8; e++) o1[e] = (bf16)((float)h1[e] * (float)w1[e]);
      bf16* btn = smem + 8192 + (cur ^ 1) * 4096;
      const int sw = (bn >> 1) & 3;
      *(bf16x8*)(btn + bn * 32 + ((bh * 2)     ^ sw) * 8) = o0;
      *(bf16x8*)(btn + bn * 32 + ((bh * 2 + 1) ^ sw) * 8) = o1;
    }
    asm volatile("s_waitcnt lgkmcnt(0)" ::: "memory");
    __builtin_amdgcn_s_barrier();
    cur ^= 1;
  }

  // ---- epilogue 1: micro = acc + U_i + U_j + mb -> global ----
  float Ui[4];
  #pragma unroll
  for (int fn = 0; fn < 4; fn++) {
    int n = wn * 64 + fn * 16 + lr;
    Ui[fn] = U[(size_t)i * INDD + n] + micro_b[n];
  }
  #pragma unroll
  for (int fm = 0; fm < 4; fm++) {
    #pragma unroll
    for (int r = 0; r < 4; r++) {
      int j = j0 + wj * 64 + fm * 16 + g * 4 + r;
      if (j < BINS) {
        const float* Uj = U + (size_t)j * INDD;
        size_t base = (size_t)OFF_MICRO + ((size_t)i * BINS + j) * INDD;
        #pragma unroll
        for (int fn = 0; fn < 4; fn++) {
          int n = wn * 64 + fn * 16 + lr;
          out[base + n] = acc[fm][fn][r] + Ui[fn] + Uj[n];
        }
      }
    }
  }
  // make the block's stores visible to its own reads (L2 is the coherence
  // point; same block = same CU/XCD; micro region never previously loaded
  // so no stale L1 lines)
  asm volatile("s_waitcnt vmcnt(0)" ::: "memory");
  __builtin_amdgcn_s_barrier();

  // ---- epilogue 2: heads from the L2-hot just-written micro tile ----
  if (i >= 50 && i < 450) {
    const bf16* w1c = (const bf16*)(wsf + WS_W1CT);
    f32x4 acc2[2][5] = {};
    const int jg = wv * 32;
    #pragma unroll
    for (int kt2 = 0; kt2 < 4; kt2++) {
      const int k0 = kt2 * 32;
      bf16x8 bfr[5];
      #pragma unroll
      for (int fn = 0; fn < 5; fn++) {
        int q = fn * 16 + lr;
        bfr[fn] = *(const bf16x8*)(w1c + q * 128 + k0 + g * 8);
      }
      bf16x8 af2[2];
      #pragma unroll
      for (int s16 = 0; s16 < 2; s16++) {
        int j = j0 + jg + s16 * 16 + lr;
        int jc = j < BINS ? j : BINS - 1;
        const float* src = out + (size_t)OFF_MICRO + ((size_t)i * BINS + jc) * INDD + k0 + g * 8;
        float4 v0 = *(const float4*)src;
        float4 v1 = *(const float4*)(src + 4);
        af2[s16] = join8(cvt4(v0.x, v0.y, v0.z, v0.w), cvt4(v1.x, v1.y, v1.z, v1.w));
      }
      #pragma unroll
      for (int s16 = 0; s16 < 2; s16++)
        #pragma unroll
        for (int fn = 0; fn < 5; fn++)
          acc2[s16][fn] = __builtin_amdgcn_mfma_f32_16x16x32_bf16(af2[s16], bfr[fn], acc2[s16][fn], 0, 0, 0);
    }
    float w2a[4], w2b[4], b1v[4];
    #pragma unroll
    for (int fn = 0; fn < 4; fn++) {
      int q = fn * 16 + lr;
      w2a[fn] = w2[q * 2]; w2b[fn] = w2[q * 2 + 1]; b1v[fn] = b1[q];
    }
    float bm = (lr < 2) ? bmc[lr] : 0.f;
    float b2a = b2[0], b2bv = b2[1];
    #pragma unroll
    for (int s16 = 0; s16 < 2; s16++) {
      #pragma unroll
      for (int r = 0; r < 4; r++) {
        int j = j0 + jg + s16 * 16 + g * 4 + r;
        float s0 = 0.f, s1 = 0.f;
        #pragma unroll
        for (int fn = 0; fn < 4; fn++) {
          float v = fmaxf(acc2[s16][fn][r] + b1v[fn], 0.f);
          s0 += v * w2a[fn]; s1 += v * w2b[fn];
        }
        #pragma unroll
        for (int mk = 1; mk < 16; mk <<= 1) {
          s0 += __shfl_xor(s0, mk);
          s1 += __shfl_xor(s1, mk);
        }
        if (j >= 50 && j < 450) {
          size_t mo = (size_t)(i - 50) * 400 + (j - 50);
          if (lr == 0) {
            out[OFF_IH + mo * 2]     = s0 + b2a;
            out[OFF_IH + mo * 2 + 1] = s1 + b2bv;
          }
          if (lr < 2) out[OFF_MC + mo * 2 + lr] = acc2[s16][4][r] + bm;
        }
      }
    }
  }
}

// ---------------------------------------------------------------------------
// hic path from hbar (pooling factorizes). 16x16 (a,b) tiles over the [10,90)
// crop; pair-from-hbar -> MFMA (K=512,N=128) -> 3-col head (VALU).
// ---------------------------------------------------------------------------
__device__ __forceinline__ bf16x4 pair4(float4 a, float4 b) {
  bf16x4 r;
  r[0] = (bf16)((a.x + b.x) * 0.5f + a.x * b.x * PAIR_S);
  r[1] = (bf16)((a.y + b.y) * 0.5f + a.y * b.y * PAIR_S);
  r[2] = (bf16)((a.z + b.z) * 0.5f + a.z * b.z * PAIR_S);
  r[3] = (bf16)((a.w + b.w) * 0.5f + a.w * b.w * PAIR_S);
  return r;
}

__global__ __launch_bounds__(256, 2)
void hic_kernel(const float* __restrict__ hbar, const float* __restrict__ wsf,
                const float* __restrict__ hicb, const float* __restrict__ whic,
                const float* __restrict__ bhic, float* __restrict__ out) {
  __shared__ float ha_lds[16][36];
  __shared__ float hb_lds[16][36];
  __shared__ bf16 pair_lds[256][36];
  __shared__ bf16 bt_lds[128][36];
  const int t = threadIdx.x;
  const int wv = t >> 6, l = t & 63;
  const int lr = l & 15, g = l >> 4;
  const int a0 = 10 + blockIdx.x * 16, b0 = 10 + blockIdx.y * 16;
  const bf16* hwt = (const bf16*)(wsf + WS_HWT);
  f32x4 acc[4][8] = {};
  for (int kt = 0; kt < 16; kt++) {
    const int k0 = kt * 32;
    if (t < 64) {
      int row = t >> 2, c = (t & 3) * 8;
      const float* src = hbar + (size_t)(a0 + row) * HID + k0 + c;
      *(float4*)&ha_lds[row][c]     = *(const float4*)src;
      *(float4*)&ha_lds[row][c + 4] = *(const float4*)(src + 4);
    } else if (t < 128) {
      int tt = t - 64;
      int row = tt >> 2, c = (tt & 3) * 8;
      const float* src = hbar + (size_t)(b0 + row) * HID + k0 + c;
      *(float4*)&hb_lds[row][c]     = *(const float4*)src;
      *(float4*)&hb_lds[row][c + 4] = *(const float4*)(src + 4);
    } else {
      int tt = t - 128;
      #pragma unroll
      for (int rep = 0; rep < 4; rep++) {
        int chunk = tt * 4 + rep;
        int n = chunk >> 2, part = chunk & 3;
        bf16x8 v = *(const bf16x8*)(hwt + (size_t)n * HID + k0 + part * 8);
        *(bf16x4*)&bt_lds[n][part * 8]     = __builtin_shufflevector(v, v, 0, 1, 2, 3);
        *(bf16x4*)&bt_lds[n][part * 8 + 4] = __builtin_shufflevector(v, v, 4, 5, 6, 7);
      }
    }
    __syncthreads();
    {
      int m = t;
      const float* pa = &ha_lds[m >> 4][0];
      const float* pb = &hb_lds[m & 15][0];
      #pragma unroll
      for (int c = 0; c < 4; c++) {
        float4 av0 = *(const float4*)(pa + c * 8);
        float4 av1 = *(const float4*)(pa + c * 8 + 4);
        float4 bv0 = *(const float4*)(pb + c * 8);
        float4 bv1 = *(const float4*)(pb + c * 8 + 4);
        *(bf16x4*)&pair_lds[m][c * 8]     = pair4(av0, bv0);
        *(bf16x4*)&pair_lds[m][c * 8 + 4] = pair4(av1, bv1);
      }
    }
    __syncthreads();
    bf16x8 af[4], bfr[8];
    #pragma unroll
    for (int fm = 0; fm < 4; fm++) {
      int row = wv * 64 + fm * 16 + lr;
      af[fm] = join8(*(const bf16x4*)&pair_lds[row][g * 8],
                     *(const bf16x4*)&pair_lds[row][g * 8 + 4]);
    }
    #pragma unroll
    for (int fn = 0; fn < 8; fn++) {
      int col = fn * 16 + lr;
      bfr[fn] = join8(*(const bf16x4*)&bt_lds[col][g * 8],
                      *(const bf16x4*)&bt_lds[col][g * 8 + 4]);
    }
    #pragma unroll
    for (int fm = 0; fm < 4; fm++)
      #pragma unroll
      for (int fn = 0; fn < 8; fn++)
        acc[fm][fn] = __builtin_amdgcn_mfma_f32_16x16x32_bf16(af[fm], bfr[fn], acc[fm][fn], 0, 0, 0);
    __syncthreads();
  }
  float wh0[8], wh1[8], wh2[8], hbv[8];
  #pragma unroll
  for (int fn = 0; fn < 8; fn++) {
    int n = fn * 16 + lr;
    wh0[fn] = whic[n * 3]; wh1[fn] = whic[n * 3 + 1]; wh2[fn] = whic[n * 3 + 2];
    hbv[fn] = hicb[n];
  }
  float bh0 = bhic[0], bh1 = bhic[1], bh2 = bhic[2];
  #pragma unroll
  for (int fm = 0; fm < 4; fm++) {
    #pragma unroll
    for (int r = 0; r < 4; r++) {
      int m = wv * 64 + fm * 16 + g * 4 + r;
      float s0 = 0.f, s1 = 0.f, s2 = 0.f;
      #pragma unroll
      for (int fn = 0; fn < 8; fn++) {
        float v = acc[fm][fn][r] + hbv[fn];
        s0 += v * wh0[fn]; s1 += v * wh1[fn]; s2 += v * wh2[fn];
      }
      #pragma unroll
      for (int mk = 1; mk < 16; mk <<= 1) {
        s0 += __shfl_xor(s0, mk);
        s1 += __shfl_xor(s1, mk);
        s2 += __shfl_xor(s2, mk);
      }
      if (lr == 0) {
        int aa = a0 + (m >> 4) - 10, bb = b0 + (m & 15) - 10;
        size_t o = (size_t)OFF_HIC + (size_t)(aa * 80 + bb) * 3;
        out[o] = s0 + bh0; out[o + 1] = s1 + bh1; out[o + 2] = s2 + bh2;
      }
    }
  }
}

// ---------------------------------------------------------------------------
extern "C" void kernel_launch(void* const* d_in, const int* in_sizes, int n_in,
                              void* d_out, int out_size, void* d_ws, size_t ws_size,
                              hipStream_t stream) {
  (void)in_sizes; (void)n_in; (void)out_size; (void)ws_size;
  const float* x    = (const float*)d_in[0];
  const float* pw1  = (const float*)d_in[1];
  const float* pb1  = (const float*)d_in[2];
  const float* pw2  = (const float*)d_in[3];
  const float* pb2  = (const float*)d_in[4];
  const float* mw   = (const float*)d_in[5];
  const float* mb   = (const float*)d_in[6];
  const float* hw   = (const float*)d_in[7];
  const float* hb   = (const float*)d_in[8];
  const float* wmc  = (const float*)d_in[9];
  const float* bmc  = (const float*)d_in[10];
  const float* wih1 = (const float*)d_in[11];
  const float* bih1 = (const float*)d_in[12];
  const float* wih2 = (const float*)d_in[13];
  const float* bih2 = (const float*)d_in[14];
  const float* whic = (const float*)d_in[15];
  const float* bhic = (const float*)d_in[16];
  float* out = (float*)d_out;
  float* ws  = (float*)d_ws;

  zero_init<<<250, 256, 0, stream>>>(ws);                          // H1, H
  // gemm1: H1 += x @ p_w1            (relu+b1 applied by gemm2's A-read)
  gemm_ks<<<dim3(8, 8, 4), 256, 0, stream>>>(x, pw1, nullptr, ws, 500, 512, 256, 0, 1.f);
  // gemm2: H += relu(H1 + b1) @ p_w2 (b2 applied by consumers)
  gemm_ks<<<dim3(8, 8, 2), 256, 0, stream>>>(ws, pw2, pb1, ws + WS_H, 500, 512, 256, 1, 1.f);
  post_h<<<2252, 256, 0, stream>>>(ws + WS_H, pb2, mw, hw, wih1, wmc, ws);   // also zeros U
  // U += 0.5 * (H + b2) @ micro_w    (mb applied in fused epilogue)
  gemm_ks<<<dim3(8, 2, 4), 256, 0, stream>>>(ws + WS_H, mw, pb2, ws + WS_U, 500, 128, 128, 0, 0.5f);
  fused_micro_heads<<<dim3(500, 4), 256, 0, stream>>>(ws, mb, bih1, wih2, bmc, bih2, out);
  hic_kernel<<<dim3(5, 5), 256, 0, stream>>>(ws + WS_HBAR, ws, hb, whic, bhic, out);
}

// Round 9
// 167.290 us; speedup vs baseline: 1.0325x; 1.0325x over previous
//
#include <hip/hip_runtime.h>

// Problem constants
#define BINS 500
#define HID  512
#define INDD 128
#define PAIR_S 0.044194173824159216f   // 1/sqrt(512)

// d_out float offsets (outputs concatenated flat: out_mc, out_ih, micro, out_hic)
#define OFF_MC    0
#define OFF_IH    320000
#define OFF_MICRO 640000
#define OFF_HIC   32640000

// ws float offsets.
// [0..256000) holds H1 (gemm1 partial sums, dead after gemm2), then reused:
//   U at 0 (500x128 f32), MWT at 64000 (bf16[128][512] = s*micro_w^T),
//   HBF at 96768 (bf16[500][512] = h+b2)
#define WS_U     0
#define WS_MWT   64000
#define WS_HBF   96768
#define WS_H     256000    // 500*512 f32 (h partial sums, no bias)
#define WS_HBAR  512000    // 100*512 f32 (pooled h+b2)
#define WS_HWT   563200    // bf16[128][512]  (hic_w^T)
#define WS_W1CT  595968    // bf16[80][128]   (head_ih_w1 | head_mc_w, transposed)

typedef __bf16 bf16;
typedef bf16 bf16x4 __attribute__((ext_vector_type(4)));
typedef bf16 bf16x8 __attribute__((ext_vector_type(8)));
typedef float f32x4 __attribute__((ext_vector_type(4)));

__device__ __forceinline__ bf16x8 join8(bf16x4 lo, bf16x4 hi) {
  return __builtin_shufflevector(lo, hi, 0, 1, 2, 3, 4, 5, 6, 7);
}
__device__ __forceinline__ bf16x4 cvt4(float a, float b, float c, float d) {
  bf16x4 r; r[0] = (bf16)a; r[1] = (bf16)b; r[2] = (bf16)c; r[3] = (bf16)d; return r;
}

// ---------------------------------------------------------------------------
// zero_init: zero H1 and H accumulators (proper grid, float4 stores).
// ---------------------------------------------------------------------------
__global__ void zero_init(float* __restrict__ ws) {
  int idx = (blockIdx.x * 256 + threadIdx.x) * 4;
  float4 z = {0.f, 0.f, 0.f, 0.f};
  *(float4*)(ws + idx) = z;            // H1
  *(float4*)(ws + WS_H + idx) = z;     // H
}

// ---------------------------------------------------------------------------
// Split-K GEMM: C += scale * (opA(A) @ B), opA = relu(a + abias) | (a + abias) | a.
// blockIdx.z = K-slice; epilogue atomicAdd. C must be zeroed before launch.
// ---------------------------------------------------------------------------
__global__ __launch_bounds__(256, 2)
void gemm_ks(const float* __restrict__ A, const float* __restrict__ B,
             const float* __restrict__ abias, float* __restrict__ C,
             int M, int N, int K_per, int a_relu, float scale) {
  __shared__ float a_lds[64][36];
  __shared__ float bt_lds[64][36];
  const int t = threadIdx.x;
  const int w = t >> 6, l = t & 63;
  const int lr = l & 15, g = l >> 4;
  const int r0 = blockIdx.x * 64, n0 = blockIdx.y * 64;
  const int kbase = blockIdx.z * K_per;
  f32x4 acc[4] = {};
  for (int kq = 0; kq < K_per; kq += 32) {
    const int k0 = kbase + kq;
    { // stage A rows (+ optional bias/relu)
      int row = t >> 2, kc = (t & 3) * 8;
      int gr = r0 + row; gr = gr < M ? gr : M - 1;
      const float* src = A + (size_t)gr * K_per * gridDim.z + k0 + kc;
      float4 v0 = *(const float4*)src;
      float4 v1 = *(const float4*)(src + 4);
      if (abias) {
        const float* bp = abias + k0 + kc;
        v0.x += bp[0]; v0.y += bp[1]; v0.z += bp[2]; v0.w += bp[3];
        v1.x += bp[4]; v1.y += bp[5]; v1.z += bp[6]; v1.w += bp[7];
        if (a_relu) {
          v0.x = fmaxf(v0.x, 0.f); v0.y = fmaxf(v0.y, 0.f);
          v0.z = fmaxf(v0.z, 0.f); v0.w = fmaxf(v0.w, 0.f);
          v1.x = fmaxf(v1.x, 0.f); v1.y = fmaxf(v1.y, 0.f);
          v1.z = fmaxf(v1.z, 0.f); v1.w = fmaxf(v1.w, 0.f);
        }
      }
      *(float4*)&a_lds[row][kc]     = v0;
      *(float4*)&a_lds[row][kc + 4] = v1;
    }
    { // stage B^T (coalesced across lanes)
      int n = t & 63, ks = (t >> 6) * 8;
      const float* src = B + (size_t)(k0 + ks) * N + n0 + n;
      #pragma unroll
      for (int s = 0; s < 8; s++) bt_lds[n][ks + s] = src[(size_t)s * N];
    }
    __syncthreads();
    bf16x8 ahi, alo;
    {
      int row = w * 16 + lr;
      float4 u0 = *(const float4*)&a_lds[row][g * 8];
      float4 u1 = *(const float4*)&a_lds[row][g * 8 + 4];
      float v[8] = {u0.x, u0.y, u0.z, u0.w, u1.x, u1.y, u1.z, u1.w};
      #pragma unroll
      for (int e = 0; e < 8; e++) {
        bf16 h = (bf16)v[e];
        ahi[e] = h; alo[e] = (bf16)(v[e] - (float)h);
      }
    }
    #pragma unroll
    for (int fn = 0; fn < 4; fn++) {
      int col = fn * 16 + lr;
      float4 u0 = *(const float4*)&bt_lds[col][g * 8];
      float4 u1 = *(const float4*)&bt_lds[col][g * 8 + 4];
      float v[8] = {u0.x, u0.y, u0.z, u0.w, u1.x, u1.y, u1.z, u1.w};
      bf16x8 bhi, blo;
      #pragma unroll
      for (int e = 0; e < 8; e++) {
        bf16 h = (bf16)v[e];
        bhi[e] = h; blo[e] = (bf16)(v[e] - (float)h);
      }
      acc[fn] = __builtin_amdgcn_mfma_f32_16x16x32_bf16(ahi, bhi, acc[fn], 0, 0, 0);
      acc[fn] = __builtin_amdgcn_mfma_f32_16x16x32_bf16(ahi, blo, acc[fn], 0, 0, 0);
      acc[fn] = __builtin_amdgcn_mfma_f32_16x16x32_bf16(alo, bhi, acc[fn], 0, 0, 0);
    }
    __syncthreads();
  }
  #pragma unroll
  for (int fn = 0; fn < 4; fn++) {
    int col = n0 + fn * 16 + lr;
    #pragma unroll
    for (int r = 0; r < 4; r++) {
      int row = r0 + w * 16 + g * 4 + r;
      if (row < M) atomicAdd(&C[(size_t)row * N + col], acc[fn][r] * scale);
    }
  }
}

// ---------------------------------------------------------------------------
// post_h: HBF = bf16(h+b2), MWT = bf16(s*micro_w^T), hbar pool (of h+b2),
// hwt/w1c weight prep, and zero the U accumulator (H1 region now dead).
// ---------------------------------------------------------------------------
__global__ void post_h(const float* __restrict__ h, const float* __restrict__ b2,
                       const float* __restrict__ micro_w,
                       const float* __restrict__ hic_w, const float* __restrict__ w_ih1,
                       const float* __restrict__ w_mc, float* __restrict__ ws) {
  int g = blockIdx.x * 256 + threadIdx.x;
  if (g < 256000) {
    bf16* hbf = (bf16*)(ws + WS_HBF);
    int k = g & (HID - 1);
    hbf[g] = (bf16)(h[g] + b2[k]);
  } else if (g < 256000 + 65536) {
    int gg = g - 256000;
    int n = gg >> 9, k = gg & 511;
    bf16* mwt = (bf16*)(ws + WS_MWT);
    mwt[gg] = (bf16)(PAIR_S * micro_w[k * INDD + n]);
  } else if (g < 256000 + 65536 + 51200) {
    int gg = g - (256000 + 65536);
    int a = gg >> 9, k = gg & (HID - 1);
    const float* p = h + (size_t)(a * 5) * HID + k;
    ws[WS_HBAR + gg] = 0.2f * (p[0] + p[HID] + p[2 * HID] + p[3 * HID] + p[4 * HID]) + b2[k];
  } else if (g < 256000 + 65536 + 51200 + 65536) {
    int gg = g - (256000 + 65536 + 51200);
    int n = gg >> 9, k = gg & 511;
    bf16* hwt = (bf16*)(ws + WS_HWT);
    hwt[gg] = (bf16)hic_w[k * INDD + n];
  } else if (g < 256000 + 65536 + 51200 + 65536 + 10240) {
    int gg = g - (256000 + 65536 + 51200 + 65536);
    int n = gg >> 7, k = gg & 127;
    float v = 0.f;
    if (n < 64) v = w_ih1[k * 64 + n];
    else if (n < 66) v = w_mc[k * 2 + (n - 64)];
    bf16* w1c = (bf16*)(ws + WS_W1CT);
    w1c[gg] = (bf16)v;
  } else if (g < 256000 + 65536 + 51200 + 65536 + 10240 + 64000) {
    int gg = g - (256000 + 65536 + 51200 + 65536 + 10240);
    ws[WS_U + gg] = 0.f;               // zero U accumulator
  }
}

// ---------------------------------------------------------------------------
// fused micro (R5 structure, 78us): Block = 128j x 128n (i fixed), 4 waves,
// BK=32 dbuf, counted vmcnt, inline B'-gen (HBF[i]*MWT in regs).
// launch_bounds(256,4): 64 VGPR + 64 AGPR = 128 regs -> 4 waves/SIMD.
// ---------------------------------------------------------------------------
__global__ __launch_bounds__(256, 4)
void fused_micro(const float* __restrict__ wsf, const float* __restrict__ micro_b,
                 float* __restrict__ out) {
  __shared__ bf16 Ht[2][128 * 32];
  __shared__ bf16 Bt[2][128 * 32];
  const int t = threadIdx.x;
  const int wv = t >> 6, l = t & 63;
  const int wj = wv >> 1, wn = wv & 1;
  const int lr = l & 15, g = l >> 4;
  const int i  = blockIdx.x;
  const int j0 = blockIdx.y * 128;
  const bf16* Hbf = (const bf16*)(wsf + WS_HBF);
  const bf16* mwt = (const bf16*)(wsf + WS_MWT);
  const float* U  = wsf + WS_U;
  const int bn = t >> 1, bh = t & 1;            // B'-gen: n-row, k-half(16)
  const int arow   = l >> 2;                    // A-stage: row within 16-group
  const int achunk = (l & 3) ^ ((l >> 3) & 3);  // pre-swizzled source 16B chunk
  const bf16* hbi = Hbf + (size_t)i * HID;
  f32x4 acc[4][4] = {};

  // ---- prologue: tile 0 ----
  #pragma unroll
  for (int q = 0; q < 2; q++) {
    int row = wv * 32 + q * 16 + arow;
    int jj = j0 + row; jj = jj < BINS ? jj : BINS - 1;
    __builtin_amdgcn_global_load_lds(
        (const __attribute__((address_space(1))) void*)(Hbf + (size_t)jj * HID + achunk * 8),
        (__attribute__((address_space(3))) void*)(&Ht[0][(wv * 32 + q * 16) * 32]),
        16, 0, 0);
  }
  {
    bf16x8 w0 = *(const bf16x8*)(mwt + (size_t)bn * HID + bh * 16);
    bf16x8 w1 = *(const bf16x8*)(mwt + (size_t)bn * HID + bh * 16 + 8);
    bf16x8 h0 = *(const bf16x8*)(hbi + bh * 16);
    bf16x8 h1 = *(const bf16x8*)(hbi + bh * 16 + 8);
    bf16x8 o0, o1;
    #pragma unroll
    for (int e = 0; e < 8; e++) o0[e] = (bf16)((float)h0[e] * (float)w0[e]);
    #pragma unroll
    for (int e = 0; e < 8; e++) o1[e] = (bf16)((float)h1[e] * (float)w1[e]);
    const int sw = (bn >> 1) & 3;
    *(bf16x8*)(&Bt[0][0] + bn * 32 + ((bh * 2)     ^ sw) * 8) = o0;
    *(bf16x8*)(&Bt[0][0] + bn * 32 + ((bh * 2 + 1) ^ sw) * 8) = o1;
  }
  asm volatile("s_waitcnt vmcnt(0) lgkmcnt(0)" ::: "memory");
  __builtin_amdgcn_s_barrier();

  // ---- main loop: 16 K-steps of 32 ----
  int cur = 0;
  for (int kt = 0; kt < 16; kt++) {
    const bf16* htc = &Ht[cur][0];
    const bf16* btc = &Bt[cur][0];
    bf16x8 w0, w1, h0, h1;
    if (kt < 15) {
      const int kn = (kt + 1) * 32;
      w0 = *(const bf16x8*)(mwt + (size_t)bn * HID + kn + bh * 16);
      w1 = *(const bf16x8*)(mwt + (size_t)bn * HID + kn + bh * 16 + 8);
      h0 = *(const bf16x8*)(hbi + kn + bh * 16);
      h1 = *(const bf16x8*)(hbi + kn + bh * 16 + 8);
      #pragma unroll
      for (int q = 0; q < 2; q++) {
        int row = wv * 32 + q * 16 + arow;
        int jj = j0 + row; jj = jj < BINS ? jj : BINS - 1;
        __builtin_amdgcn_global_load_lds(
            (const __attribute__((address_space(1))) void*)(Hbf + (size_t)jj * HID + kn + achunk * 8),
            (__attribute__((address_space(3))) void*)(&Ht[cur ^ 1][(wv * 32 + q * 16) * 32]),
            16, 0, 0);
      }
      asm volatile("s_waitcnt vmcnt(6)" ::: "memory");
    } else {
      asm volatile("s_waitcnt vmcnt(0)" ::: "memory");
    }
    bf16x8 af[4], bfr[4];
    const int s = g ^ ((lr >> 1) & 3);
    #pragma unroll
    for (int fm = 0; fm < 4; fm++)
      af[fm] = *(const bf16x8*)(htc + (wj * 64 + fm * 16 + lr) * 32 + s * 8);
    #pragma unroll
    for (int fn = 0; fn < 4; fn++)
      bfr[fn] = *(const bf16x8*)(btc + (wn * 64 + fn * 16 + lr) * 32 + s * 8);
    #pragma unroll
    for (int fm = 0; fm < 4; fm++)
      #pragma unroll
      for (int fn = 0; fn < 4; fn++)
        acc[fm][fn] = __builtin_amdgcn_mfma_f32_16x16x32_bf16(af[fm], bfr[fn], acc[fm][fn], 0, 0, 0);
    if (kt < 15) {
      bf16x8 o0, o1;
      #pragma unroll
      for (int e = 0; e < 8; e++) o0[e] = (bf16)((float)h0[e] * (float)w0[e]);
      #pragma unroll
      for (int e = 0; e < 8; e++) o1[e] = (bf16)((float)h1[e] * (float)w1[e]);
      bf16* btn = &Bt[cur ^ 1][0];
      const int sw = (bn >> 1) & 3;
      *(bf16x8*)(btn + bn * 32 + ((bh * 2)     ^ sw) * 8) = o0;
      *(bf16x8*)(btn + bn * 32 + ((bh * 2 + 1) ^ sw) * 8) = o1;
    }
    asm volatile("s_waitcnt lgkmcnt(0)" ::: "memory");
    __builtin_amdgcn_s_barrier();
    cur ^= 1;
  }

  // ---- epilogue: out = acc + U_i + U_j + mb ----
  float Ui[4];
  #pragma unroll
  for (int fn = 0; fn < 4; fn++) {
    int n = wn * 64 + fn * 16 + lr;
    Ui[fn] = U[(size_t)i * INDD + n] + micro_b[n];
  }
  #pragma unroll
  for (int fm = 0; fm < 4; fm++) {
    #pragma unroll
    for (int r = 0; r < 4; r++) {
      int j = j0 + wj * 64 + fm * 16 + g * 4 + r;
      if (j < BINS) {
        const float* Uj = U + (size_t)j * INDD;
        size_t base = (size_t)OFF_MICRO + ((size_t)i * BINS + j) * INDD;
        #pragma unroll
        for (int fn = 0; fn < 4; fn++) {
          int n = wn * 64 + fn * 16 + lr;
          out[base + n] = acc[fm][fn][r] + Ui[fn] + Uj[n];
        }
      }
    }
  }
}

// ---------------------------------------------------------------------------
// heads_direct: no LDS, no barriers. 256 crop-pairs/block (4 waves x 64 rows).
// A-fragments read straight from global micro (f32, contiguous per lane in
// the k=n dim), converted to bf16 (bit-identical to old heads_kernel);
// B-fragments (w1c, 20KB) straight from L2. Pure load/MFMA stream.
// ---------------------------------------------------------------------------
__global__ __launch_bounds__(256, 2)
void heads_direct(const float* __restrict__ micro, const float* __restrict__ wsf,
                  const float* __restrict__ b1, const float* __restrict__ w2,
                  const float* __restrict__ bmc, const float* __restrict__ b2,
                  float* __restrict__ out) {
  const int t = threadIdx.x;
  const int wv = t >> 6, l = t & 63;
  const int lr = l & 15, g = l >> 4;
  const int mm0 = blockIdx.x * 256;
  const bf16* w1c = (const bf16*)(wsf + WS_W1CT);
  // row address in micro for each fm: (50+mm/400)*500 + 50 + mm%400
  int mrow[4];
  #pragma unroll
  for (int fm = 0; fm < 4; fm++) {
    int mm = mm0 + wv * 64 + fm * 16 + lr;
    mrow[fm] = 25050 + mm + 100 * (mm / 400);
  }
  f32x4 acc[4][5] = {};
  #pragma unroll
  for (int kt = 0; kt < 4; kt++) {
    const int k0 = kt * 32;
    bf16x8 bfr[5];
    #pragma unroll
    for (int fn = 0; fn < 5; fn++) {
      int q = fn * 16 + lr;
      bfr[fn] = *(const bf16x8*)(w1c + q * 128 + k0 + g * 8);
    }
    #pragma unroll
    for (int fm = 0; fm < 4; fm++) {
      const float* src = micro + (size_t)mrow[fm] * INDD + k0 + g * 8;
      float4 v0 = *(const float4*)src;
      float4 v1 = *(const float4*)(src + 4);
      bf16x8 af = join8(cvt4(v0.x, v0.y, v0.z, v0.w), cvt4(v1.x, v1.y, v1.z, v1.w));
      #pragma unroll
      for (int fn = 0; fn < 5; fn++)
        acc[fm][fn] = __builtin_amdgcn_mfma_f32_16x16x32_bf16(af, bfr[fn], acc[fm][fn], 0, 0, 0);
    }
  }
  float w2a[4], w2b[4], b1v[4];
  #pragma unroll
  for (int fn = 0; fn < 4; fn++) {
    int q = fn * 16 + lr;
    w2a[fn] = w2[q * 2]; w2b[fn] = w2[q * 2 + 1]; b1v[fn] = b1[q];
  }
  float bm = (lr < 2) ? bmc[lr] : 0.f;
  float b2a = b2[0], b2bv = b2[1];
  #pragma unroll
  for (int fm = 0; fm < 4; fm++) {
    #pragma unroll
    for (int r = 0; r < 4; r++) {
      int m = wv * 64 + fm * 16 + g * 4 + r;
      float s0 = 0.f, s1 = 0.f;
      #pragma unroll
      for (int fn = 0; fn < 4; fn++) {
        float v = fmaxf(acc[fm][fn][r] + b1v[fn], 0.f);
        s0 += v * w2a[fn]; s1 += v * w2b[fn];
      }
      #pragma unroll
      for (int mk = 1; mk < 16; mk <<= 1) {
        s0 += __shfl_xor(s0, mk);
        s1 += __shfl_xor(s1, mk);
      }
      size_t mo = (size_t)(mm0 + m);
      if (lr == 0) {
        out[OFF_IH + mo * 2]     = s0 + b2a;
        out[OFF_IH + mo * 2 + 1] = s1 + b2bv;
      }
      if (lr < 2) out[OFF_MC + mo * 2 + lr] = acc[fm][4][r] + bm;
    }
  }
}

// ---------------------------------------------------------------------------
// hic path from hbar (pooling factorizes). 16x16 (a,b) tiles over the [10,90)
// crop; pair-from-hbar -> MFMA (K=512,N=128) -> 3-col head (VALU).
// ---------------------------------------------------------------------------
__device__ __forceinline__ bf16x4 pair4(float4 a, float4 b) {
  bf16x4 r;
  r[0] = (bf16)((a.x + b.x) * 0.5f + a.x * b.x * PAIR_S);
  r[1] = (bf16)((a.y + b.y) * 0.5f + a.y * b.y * PAIR_S);
  r[2] = (bf16)((a.z + b.z) * 0.5f + a.z * b.z * PAIR_S);
  r[3] = (bf16)((a.w + b.w) * 0.5f + a.w * b.w * PAIR_S);
  return r;
}

__global__ __launch_bounds__(256, 2)
void hic_kernel(const float* __restrict__ hbar, const float* __restrict__ wsf,
                const float* __restrict__ hicb, const float* __restrict__ whic,
                const float* __restrict__ bhic, float* __restrict__ out) {
  __shared__ float ha_lds[16][36];
  __shared__ float hb_lds[16][36];
  __shared__ bf16 pair_lds[256][36];
  __shared__ bf16 bt_lds[128][36];
  const int t = threadIdx.x;
  const int wv = t >> 6, l = t & 63;
  const int lr = l & 15, g = l >> 4;
  const int a0 = 10 + blockIdx.x * 16, b0 = 10 + blockIdx.y * 16;
  const bf16* hwt = (const bf16*)(wsf + WS_HWT);
  f32x4 acc[4][8] = {};
  for (int kt = 0; kt < 16; kt++) {
    const int k0 = kt * 32;
    if (t < 64) {
      int row = t >> 2, c = (t & 3) * 8;
      const float* src = hbar + (size_t)(a0 + row) * HID + k0 + c;
      *(float4*)&ha_lds[row][c]     = *(const float4*)src;
      *(float4*)&ha_lds[row][c + 4] = *(const float4*)(src + 4);
    } else if (t < 128) {
      int tt = t - 64;
      int row = tt >> 2, c = (tt & 3) * 8;
      const float* src = hbar + (size_t)(b0 + row) * HID + k0 + c;
      *(float4*)&hb_lds[row][c]     = *(const float4*)src;
      *(float4*)&hb_lds[row][c + 4] = *(const float4*)(src + 4);
    } else {
      int tt = t - 128;
      #pragma unroll
      for (int rep = 0; rep < 4; rep++) {
        int chunk = tt * 4 + rep;
        int n = chunk >> 2, part = chunk & 3;
        bf16x8 v = *(const bf16x8*)(hwt + (size_t)n * HID + k0 + part * 8);
        *(bf16x4*)&bt_lds[n][part * 8]     = __builtin_shufflevector(v, v, 0, 1, 2, 3);
        *(bf16x4*)&bt_lds[n][part * 8 + 4] = __builtin_shufflevector(v, v, 4, 5, 6, 7);
      }
    }
    __syncthreads();
    {
      int m = t;
      const float* pa = &ha_lds[m >> 4][0];
      const float* pb = &hb_lds[m & 15][0];
      #pragma unroll
      for (int c = 0; c < 4; c++) {
        float4 av0 = *(const float4*)(pa + c * 8);
        float4 av1 = *(const float4*)(pa + c * 8 + 4);
        float4 bv0 = *(const float4*)(pb + c * 8);
        float4 bv1 = *(const float4*)(pb + c * 8 + 4);
        *(bf16x4*)&pair_lds[m][c * 8]     = pair4(av0, bv0);
        *(bf16x4*)&pair_lds[m][c * 8 + 4] = pair4(av1, bv1);
      }
    }
    __syncthreads();
    bf16x8 af[4], bfr[8];
    #pragma unroll
    for (int fm = 0; fm < 4; fm++) {
      int row = wv * 64 + fm * 16 + lr;
      af[fm] = join8(*(const bf16x4*)&pair_lds[row][g * 8],
                     *(const bf16x4*)&pair_lds[row][g * 8 + 4]);
    }
    #pragma unroll
    for (int fn = 0; fn < 8; fn++) {
      int col = fn * 16 + lr;
      bfr[fn] = join8(*(const bf16x4*)&bt_lds[col][g * 8],
                      *(const bf16x4*)&bt_lds[col][g * 8 + 4]);
    }
    #pragma unroll
    for (int fm = 0; fm < 4; fm++)
      #pragma unroll
      for (int fn = 0; fn < 8; fn++)
        acc[fm][fn] = __builtin_amdgcn_mfma_f32_16x16x32_bf16(af[fm], bfr[fn], acc[fm][fn], 0, 0, 0);
    __syncthreads();
  }
  float wh0[8], wh1[8], wh2[8], hbv[8];
  #pragma unroll
  for (int fn = 0; fn < 8; fn++) {
    int n = fn * 16 + lr;
    wh0[fn] = whic[n * 3]; wh1[fn] = whic[n * 3 + 1]; wh2[fn] = whic[n * 3 + 2];
    hbv[fn] = hicb[n];
  }
  float bh0 = bhic[0], bh1 = bhic[1], bh2 = bhic[2];
  #pragma unroll
  for (int fm = 0; fm < 4; fm++) {
    #pragma unroll
    for (int r = 0; r < 4; r++) {
      int m = wv * 64 + fm * 16 + g * 4 + r;
      float s0 = 0.f, s1 = 0.f, s2 = 0.f;
      #pragma unroll
      for (int fn = 0; fn < 8; fn++) {
        float v = acc[fm][fn][r] + hbv[fn];
        s0 += v * wh0[fn]; s1 += v * wh1[fn]; s2 += v * wh2[fn];
      }
      #pragma unroll
      for (int mk = 1; mk < 16; mk <<= 1) {
        s0 += __shfl_xor(s0, mk);
        s1 += __shfl_xor(s1, mk);
        s2 += __shfl_xor(s2, mk);
      }
      if (lr == 0) {
        int aa = a0 + (m >> 4) - 10, bb = b0 + (m & 15) - 10;
        size_t o = (size_t)OFF_HIC + (size_t)(aa * 80 + bb) * 3;
        out[o] = s0 + bh0; out[o + 1] = s1 + bh1; out[o + 2] = s2 + bh2;
      }
    }
  }
}

// ---------------------------------------------------------------------------
extern "C" void kernel_launch(void* const* d_in, const int* in_sizes, int n_in,
                              void* d_out, int out_size, void* d_ws, size_t ws_size,
                              hipStream_t stream) {
  (void)in_sizes; (void)n_in; (void)out_size; (void)ws_size;
  const float* x    = (const float*)d_in[0];
  const float* pw1  = (const float*)d_in[1];
  const float* pb1  = (const float*)d_in[2];
  const float* pw2  = (const float*)d_in[3];
  const float* pb2  = (const float*)d_in[4];
  const float* mw   = (const float*)d_in[5];
  const float* mb   = (const float*)d_in[6];
  const float* hw   = (const float*)d_in[7];
  const float* hb   = (const float*)d_in[8];
  const float* wmc  = (const float*)d_in[9];
  const float* bmc  = (const float*)d_in[10];
  const float* wih1 = (const float*)d_in[11];
  const float* bih1 = (const float*)d_in[12];
  const float* wih2 = (const float*)d_in[13];
  const float* bih2 = (const float*)d_in[14];
  const float* whic = (const float*)d_in[15];
  const float* bhic = (const float*)d_in[16];
  float* out = (float*)d_out;
  float* ws  = (float*)d_ws;

  zero_init<<<250, 256, 0, stream>>>(ws);                          // H1, H
  // gemm1: H1 += x @ p_w1            (relu+b1 applied by gemm2's A-read)
  gemm_ks<<<dim3(8, 8, 4), 256, 0, stream>>>(x, pw1, nullptr, ws, 500, 512, 256, 0, 1.f);
  // gemm2: H += relu(H1 + b1) @ p_w2 (b2 applied by consumers)
  gemm_ks<<<dim3(8, 8, 2), 256, 0, stream>>>(ws, pw2, pb1, ws + WS_H, 500, 512, 256, 1, 1.f);
  post_h<<<2252, 256, 0, stream>>>(ws + WS_H, pb2, mw, hw, wih1, wmc, ws);   // also zeros U
  // U += 0.5 * (H + b2) @ micro_w    (mb applied in fused epilogue)
  gemm_ks<<<dim3(8, 2, 4), 256, 0, stream>>>(ws + WS_H, mw, pb2, ws + WS_U, 500, 128, 128, 0, 0.5f);
  fused_micro<<<dim3(500, 4), 256, 0, stream>>>(ws, mb, out);
  heads_direct<<<625, 256, 0, stream>>>(out + OFF_MICRO, ws, bih1, wih2, bmc, bih2, out);
  hic_kernel<<<dim3(5, 5), 256, 0, stream>>>(ws + WS_HBAR, ws, hb, whic, bhic, out);
}

// Round 10
// 149.293 us; speedup vs baseline: 1.1570x; 1.1205x over previous
//
#include <hip/hip_runtime.h>

// Problem constants
#define BINS 500
#define HID  512
#define INDD 128
#define PAIR_S 0.044194173824159216f   // 1/sqrt(512)

// d_out float offsets (outputs concatenated flat: out_mc, out_ih, micro, out_hic)
#define OFF_MC    0
#define OFF_IH    320000
#define OFF_MICRO 640000
#define OFF_HIC   32640000

// ws float offsets.
// [0..256000) holds H1 (gemm1 partial sums, dead after gemm2), then reused:
//   U at 0 (500x128 f32), MWT at 64000 (bf16[128][512] = s*micro_w^T),
//   HBF at 96768 (bf16[500][512] = h+b2)
#define WS_U     0
#define WS_MWT   64000
#define WS_HBF   96768
#define WS_H     256000    // 500*512 f32 (h partial sums, no bias)
#define WS_HBAR  512000    // 100*512 f32 (pooled h+b2)
#define WS_HWT   563200    // bf16[128][512]  (hic_w^T)
#define WS_W1CT  595968    // bf16[80][128]   (head_ih_w1 | head_mc_w, transposed)

typedef __bf16 bf16;
typedef bf16 bf16x4 __attribute__((ext_vector_type(4)));
typedef bf16 bf16x8 __attribute__((ext_vector_type(8)));
typedef float f32x4 __attribute__((ext_vector_type(4)));

__device__ __forceinline__ bf16x8 join8(bf16x4 lo, bf16x4 hi) {
  return __builtin_shufflevector(lo, hi, 0, 1, 2, 3, 4, 5, 6, 7);
}
__device__ __forceinline__ bf16x4 cvt4(float a, float b, float c, float d) {
  bf16x4 r; r[0] = (bf16)a; r[1] = (bf16)b; r[2] = (bf16)c; r[3] = (bf16)d; return r;
}

// ---------------------------------------------------------------------------
// zero_init: zero H1 and H accumulators (proper grid, float4 stores).
// ---------------------------------------------------------------------------
__global__ void zero_init(float* __restrict__ ws) {
  int idx = (blockIdx.x * 256 + threadIdx.x) * 4;
  float4 z = {0.f, 0.f, 0.f, 0.f};
  *(float4*)(ws + idx) = z;            // H1
  *(float4*)(ws + WS_H + idx) = z;     // H
}

// ---------------------------------------------------------------------------
// Split-K GEMM: C += scale * (opA(A) @ B), opA = relu(a + abias) | (a + abias) | a.
// blockIdx.z = K-slice; epilogue atomicAdd. C must be zeroed before launch.
// ---------------------------------------------------------------------------
__global__ __launch_bounds__(256, 2)
void gemm_ks(const float* __restrict__ A, const float* __restrict__ B,
             const float* __restrict__ abias, float* __restrict__ C,
             int M, int N, int K_per, int a_relu, float scale) {
  __shared__ float a_lds[64][36];
  __shared__ float bt_lds[64][36];
  const int t = threadIdx.x;
  const int w = t >> 6, l = t & 63;
  const int lr = l & 15, g = l >> 4;
  const int r0 = blockIdx.x * 64, n0 = blockIdx.y * 64;
  const int kbase = blockIdx.z * K_per;
  f32x4 acc[4] = {};
  for (int kq = 0; kq < K_per; kq += 32) {
    const int k0 = kbase + kq;
    { // stage A rows (+ optional bias/relu)
      int row = t >> 2, kc = (t & 3) * 8;
      int gr = r0 + row; gr = gr < M ? gr : M - 1;
      const float* src = A + (size_t)gr * K_per * gridDim.z + k0 + kc;
      float4 v0 = *(const float4*)src;
      float4 v1 = *(const float4*)(src + 4);
      if (abias) {
        const float* bp = abias + k0 + kc;
        v0.x += bp[0]; v0.y += bp[1]; v0.z += bp[2]; v0.w += bp[3];
        v1.x += bp[4]; v1.y += bp[5]; v1.z += bp[6]; v1.w += bp[7];
        if (a_relu) {
          v0.x = fmaxf(v0.x, 0.f); v0.y = fmaxf(v0.y, 0.f);
          v0.z = fmaxf(v0.z, 0.f); v0.w = fmaxf(v0.w, 0.f);
          v1.x = fmaxf(v1.x, 0.f); v1.y = fmaxf(v1.y, 0.f);
          v1.z = fmaxf(v1.z, 0.f); v1.w = fmaxf(v1.w, 0.f);
        }
      }
      *(float4*)&a_lds[row][kc]     = v0;
      *(float4*)&a_lds[row][kc + 4] = v1;
    }
    { // stage B^T (coalesced across lanes)
      int n = t & 63, ks = (t >> 6) * 8;
      const float* src = B + (size_t)(k0 + ks) * N + n0 + n;
      #pragma unroll
      for (int s = 0; s < 8; s++) bt_lds[n][ks + s] = src[(size_t)s * N];
    }
    __syncthreads();
    bf16x8 ahi, alo;
    {
      int row = w * 16 + lr;
      float4 u0 = *(const float4*)&a_lds[row][g * 8];
      float4 u1 = *(const float4*)&a_lds[row][g * 8 + 4];
      float v[8] = {u0.x, u0.y, u0.z, u0.w, u1.x, u1.y, u1.z, u1.w};
      #pragma unroll
      for (int e = 0; e < 8; e++) {
        bf16 h = (bf16)v[e];
        ahi[e] = h; alo[e] = (bf16)(v[e] - (float)h);
      }
    }
    #pragma unroll
    for (int fn = 0; fn < 4; fn++) {
      int col = fn * 16 + lr;
      float4 u0 = *(const float4*)&bt_lds[col][g * 8];
      float4 u1 = *(const float4*)&bt_lds[col][g * 8 + 4];
      float v[8] = {u0.x, u0.y, u0.z, u0.w, u1.x, u1.y, u1.z, u1.w};
      bf16x8 bhi, blo;
      #pragma unroll
      for (int e = 0; e < 8; e++) {
        bf16 h = (bf16)v[e];
        bhi[e] = h; blo[e] = (bf16)(v[e] - (float)h);
      }
      acc[fn] = __builtin_amdgcn_mfma_f32_16x16x32_bf16(ahi, bhi, acc[fn], 0, 0, 0);
      acc[fn] = __builtin_amdgcn_mfma_f32_16x16x32_bf16(ahi, blo, acc[fn], 0, 0, 0);
      acc[fn] = __builtin_amdgcn_mfma_f32_16x16x32_bf16(alo, bhi, acc[fn], 0, 0, 0);
    }
    __syncthreads();
  }
  #pragma unroll
  for (int fn = 0; fn < 4; fn++) {
    int col = n0 + fn * 16 + lr;
    #pragma unroll
    for (int r = 0; r < 4; r++) {
      int row = r0 + w * 16 + g * 4 + r;
      if (row < M) atomicAdd(&C[(size_t)row * N + col], acc[fn][r] * scale);
    }
  }
}

// ---------------------------------------------------------------------------
// post_h (vectorized, 8 elems/thread): HBF = bf16(h+b2), MWT = bf16(s*mw^T),
// hbar pool (of h+b2), HWT = bf16(hic_w^T), w1c prep, U zero.
// Section sizes (in 8-elem units): 32000 | 8192 | 6400 | 8192 | 1280 | 8000
// ---------------------------------------------------------------------------
__global__ void post_h(const float* __restrict__ h, const float* __restrict__ b2,
                       const float* __restrict__ micro_w,
                       const float* __restrict__ hic_w, const float* __restrict__ w_ih1,
                       const float* __restrict__ w_mc, float* __restrict__ ws) {
  int g = blockIdx.x * 256 + threadIdx.x;
  if (g < 32000) {                         // HBF
    int e = g * 8, k = e & (HID - 1);
    float4 a0 = *(const float4*)(h + e),  a1 = *(const float4*)(h + e + 4);
    float4 c0 = *(const float4*)(b2 + k), c1 = *(const float4*)(b2 + k + 4);
    bf16x8 o;
    o[0] = (bf16)(a0.x + c0.x); o[1] = (bf16)(a0.y + c0.y);
    o[2] = (bf16)(a0.z + c0.z); o[3] = (bf16)(a0.w + c0.w);
    o[4] = (bf16)(a1.x + c1.x); o[5] = (bf16)(a1.y + c1.y);
    o[6] = (bf16)(a1.z + c1.z); o[7] = (bf16)(a1.w + c1.w);
    *(bf16x8*)((bf16*)(ws + WS_HBF) + e) = o;
  } else if (g < 40192) {                  // MWT (transposed, scaled)
    int gg = (g - 32000) * 8;
    int n = gg >> 9, k = gg & 511;
    bf16x8 o;
    #pragma unroll
    for (int e = 0; e < 8; e++) o[e] = (bf16)(PAIR_S * micro_w[(size_t)(k + e) * INDD + n]);
    *(bf16x8*)((bf16*)(ws + WS_MWT) + gg) = o;
  } else if (g < 46592) {                  // hbar pool
    int gg = (g - 40192) * 8;
    int a = gg >> 9, k = gg & (HID - 1);
    const float* p = h + (size_t)(a * 5) * HID + k;
    float s[8] = {};
    #pragma unroll
    for (int r = 0; r < 5; r++) {
      float4 v0 = *(const float4*)(p + r * HID);
      float4 v1 = *(const float4*)(p + r * HID + 4);
      s[0] += v0.x; s[1] += v0.y; s[2] += v0.z; s[3] += v0.w;
      s[4] += v1.x; s[5] += v1.y; s[6] += v1.z; s[7] += v1.w;
    }
    float4 c0 = *(const float4*)(b2 + k), c1 = *(const float4*)(b2 + k + 4);
    float4 o0 = {s[0] * 0.2f + c0.x, s[1] * 0.2f + c0.y, s[2] * 0.2f + c0.z, s[3] * 0.2f + c0.w};
    float4 o1 = {s[4] * 0.2f + c1.x, s[5] * 0.2f + c1.y, s[6] * 0.2f + c1.z, s[7] * 0.2f + c1.w};
    *(float4*)(ws + WS_HBAR + gg)     = o0;
    *(float4*)(ws + WS_HBAR + gg + 4) = o1;
  } else if (g < 54784) {                  // HWT (transposed)
    int gg = (g - 46592) * 8;
    int n = gg >> 9, k = gg & 511;
    bf16x8 o;
    #pragma unroll
    for (int e = 0; e < 8; e++) o[e] = (bf16)hic_w[(size_t)(k + e) * INDD + n];
    *(bf16x8*)((bf16*)(ws + WS_HWT) + gg) = o;
  } else if (g < 56064) {                  // w1c
    int gg = (g - 54784) * 8;
    int n = gg >> 7, k = gg & 127;
    bf16x8 o;
    #pragma unroll
    for (int e = 0; e < 8; e++) {
      float v = 0.f;
      if (n < 64) v = w_ih1[(k + e) * 64 + n];
      else if (n < 66) v = w_mc[(k + e) * 2 + (n - 64)];
      o[e] = (bf16)v;
    }
    *(bf16x8*)((bf16*)(ws + WS_W1CT) + gg) = o;
  } else if (g < 64064) {                  // zero U
    int gg = (g - 56064) * 8;
    float4 z = {0.f, 0.f, 0.f, 0.f};
    *(float4*)(ws + WS_U + gg)     = z;
    *(float4*)(ws + WS_U + gg + 4) = z;
  }
}

// ---------------------------------------------------------------------------
// fused micro v5: Block = 256j x 128n (i fixed), 512 thr / 8 waves
// (wave = 64j x 64n, acc[4][4] = 64 AGPR; ~128 regs -> 4 waves/SIMD,
// 48KB LDS -> 2 blocks/CU). BK=32 dbuf, counted vmcnt. B'-gen redundancy
// halved (2 j-blocks per i) and 8 elems/thread (was 16).
// ---------------------------------------------------------------------------
__global__ __launch_bounds__(512, 4)
void fused_micro(const float* __restrict__ wsf, const float* __restrict__ micro_b,
                 float* __restrict__ out) {
  __shared__ bf16 Ht[2][256 * 32];   // 2 x 16KB
  __shared__ bf16 Bt[2][128 * 32];   // 2 x 8KB
  const int t = threadIdx.x;
  const int wv = t >> 6, l = t & 63;
  const int wj = wv >> 1, wn = wv & 1;
  const int lr = l & 15, g = l >> 4;
  const int i  = blockIdx.x;
  const int j0 = blockIdx.y * 256;
  const bf16* Hbf = (const bf16*)(wsf + WS_HBF);
  const bf16* mwt = (const bf16*)(wsf + WS_MWT);
  const float* U  = wsf + WS_U;
  const int bn = t >> 2, bq = t & 3;            // B'-gen: n-row, k-quarter(8)
  const int arow   = l >> 2;                    // A-stage: row within 16-group
  const int achunk = (l & 3) ^ ((l >> 3) & 3);  // pre-swizzled source 16B chunk
  const bf16* hbi = Hbf + (size_t)i * HID;
  f32x4 acc[4][4] = {};

  // ---- prologue: tile 0 ----
  #pragma unroll
  for (int q = 0; q < 2; q++) {
    int row = wv * 32 + q * 16 + arow;
    int jj = j0 + row; jj = jj < BINS ? jj : BINS - 1;
    __builtin_amdgcn_global_load_lds(
        (const __attribute__((address_space(1))) void*)(Hbf + (size_t)jj * HID + achunk * 8),
        (__attribute__((address_space(3))) void*)(&Ht[0][(wv * 32 + q * 16) * 32]),
        16, 0, 0);
  }
  {
    bf16x8 w = *(const bf16x8*)(mwt + (size_t)bn * HID + bq * 8);
    bf16x8 hh = *(const bf16x8*)(hbi + bq * 8);
    bf16x8 o;
    #pragma unroll
    for (int e = 0; e < 8; e++) o[e] = (bf16)((float)hh[e] * (float)w[e]);
    const int slot = bq ^ ((bn >> 1) & 3);
    *(bf16x8*)(&Bt[0][0] + bn * 32 + slot * 8) = o;
  }
  asm volatile("s_waitcnt vmcnt(0) lgkmcnt(0)" ::: "memory");
  __builtin_amdgcn_s_barrier();

  // ---- main loop: 16 K-steps of 32 ----
  int cur = 0;
  for (int kt = 0; kt < 16; kt++) {
    const bf16* htc = &Ht[cur][0];
    const bf16* btc = &Bt[cur][0];
    bf16x8 w, hh;
    if (kt < 15) {
      const int kn = (kt + 1) * 32;
      // reg prefetch FIRST (older in vmcnt order than the glls)
      w  = *(const bf16x8*)(mwt + (size_t)bn * HID + kn + bq * 8);
      hh = *(const bf16x8*)(hbi + kn + bq * 8);
      #pragma unroll
      for (int q = 0; q < 2; q++) {
        int row = wv * 32 + q * 16 + arow;
        int jj = j0 + row; jj = jj < BINS ? jj : BINS - 1;
        __builtin_amdgcn_global_load_lds(
            (const __attribute__((address_space(1))) void*)(Hbf + (size_t)jj * HID + kn + achunk * 8),
            (__attribute__((address_space(3))) void*)(&Ht[cur ^ 1][(wv * 32 + q * 16) * 32]),
            16, 0, 0);
      }
      // drain only the previous tile's 2 glls; keep w,h + 2 glls in flight
      asm volatile("s_waitcnt vmcnt(4)" ::: "memory");
    } else {
      asm volatile("s_waitcnt vmcnt(0)" ::: "memory");
    }
    bf16x8 af[4], bfr[4];
    const int s = g ^ ((lr >> 1) & 3);
    #pragma unroll
    for (int fm = 0; fm < 4; fm++)
      af[fm] = *(const bf16x8*)(htc + (wj * 64 + fm * 16 + lr) * 32 + s * 8);
    #pragma unroll
    for (int fn = 0; fn < 4; fn++)
      bfr[fn] = *(const bf16x8*)(btc + (wn * 64 + fn * 16 + lr) * 32 + s * 8);
    #pragma unroll
    for (int fm = 0; fm < 4; fm++)
      #pragma unroll
      for (int fn = 0; fn < 4; fn++)
        acc[fm][fn] = __builtin_amdgcn_mfma_f32_16x16x32_bf16(af[fm], bfr[fn], acc[fm][fn], 0, 0, 0);
    if (kt < 15) {
      bf16x8 o;
      #pragma unroll
      for (int e = 0; e < 8; e++) o[e] = (bf16)((float)hh[e] * (float)w[e]);
      const int slot = bq ^ ((bn >> 1) & 3);
      *(bf16x8*)(&Bt[cur ^ 1][0] + bn * 32 + slot * 8) = o;
    }
    asm volatile("s_waitcnt lgkmcnt(0)" ::: "memory");
    __builtin_amdgcn_s_barrier();
    cur ^= 1;
  }

  // ---- epilogue: out = acc + U_i + U_j + mb ----
  float Ui[4];
  #pragma unroll
  for (int fn = 0; fn < 4; fn++) {
    int n = wn * 64 + fn * 16 + lr;
    Ui[fn] = U[(size_t)i * INDD + n] + micro_b[n];
  }
  #pragma unroll
  for (int fm = 0; fm < 4; fm++) {
    #pragma unroll
    for (int r = 0; r < 4; r++) {
      int j = j0 + wj * 64 + fm * 16 + g * 4 + r;
      if (j < BINS) {
        const float* Uj = U + (size_t)j * INDD;
        size_t base = (size_t)OFF_MICRO + ((size_t)i * BINS + j) * INDD;
        #pragma unroll
        for (int fn = 0; fn < 4; fn++) {
          int n = wn * 64 + fn * 16 + lr;
          out[base + n] = acc[fm][fn][r] + Ui[fn] + Uj[n];
        }
      }
    }
  }
}

// ---------------------------------------------------------------------------
// heads_direct: no LDS, no barriers. 256 crop-pairs/block (4 waves x 64 rows).
// A-fragments read straight from global micro (f32, contiguous per lane),
// converted to bf16 (bit-identical); B-fragments (w1c, 20KB) from L2.
// ---------------------------------------------------------------------------
__global__ __launch_bounds__(256, 2)
void heads_direct(const float* __restrict__ micro, const float* __restrict__ wsf,
                  const float* __restrict__ b1, const float* __restrict__ w2,
                  const float* __restrict__ bmc, const float* __restrict__ b2,
                  float* __restrict__ out) {
  const int t = threadIdx.x;
  const int wv = t >> 6, l = t & 63;
  const int lr = l & 15, g = l >> 4;
  const int mm0 = blockIdx.x * 256;
  const bf16* w1c = (const bf16*)(wsf + WS_W1CT);
  int mrow[4];
  #pragma unroll
  for (int fm = 0; fm < 4; fm++) {
    int mm = mm0 + wv * 64 + fm * 16 + lr;
    mrow[fm] = 25050 + mm + 100 * (mm / 400);
  }
  f32x4 acc[4][5] = {};
  #pragma unroll
  for (int kt = 0; kt < 4; kt++) {
    const int k0 = kt * 32;
    bf16x8 bfr[5];
    #pragma unroll
    for (int fn = 0; fn < 5; fn++) {
      int q = fn * 16 + lr;
      bfr[fn] = *(const bf16x8*)(w1c + q * 128 + k0 + g * 8);
    }
    #pragma unroll
    for (int fm = 0; fm < 4; fm++) {
      const float* src = micro + (size_t)mrow[fm] * INDD + k0 + g * 8;
      float4 v0 = *(const float4*)src;
      float4 v1 = *(const float4*)(src + 4);
      bf16x8 af = join8(cvt4(v0.x, v0.y, v0.z, v0.w), cvt4(v1.x, v1.y, v1.z, v1.w));
      #pragma unroll
      for (int fn = 0; fn < 5; fn++)
        acc[fm][fn] = __builtin_amdgcn_mfma_f32_16x16x32_bf16(af, bfr[fn], acc[fm][fn], 0, 0, 0);
    }
  }
  float w2a[4], w2b[4], b1v[4];
  #pragma unroll
  for (int fn = 0; fn < 4; fn++) {
    int q = fn * 16 + lr;
    w2a[fn] = w2[q * 2]; w2b[fn] = w2[q * 2 + 1]; b1v[fn] = b1[q];
  }
  float bm = (lr < 2) ? bmc[lr] : 0.f;
  float b2a = b2[0], b2bv = b2[1];
  #pragma unroll
  for (int fm = 0; fm < 4; fm++) {
    #pragma unroll
    for (int r = 0; r < 4; r++) {
      int m = wv * 64 + fm * 16 + g * 4 + r;
      float s0 = 0.f, s1 = 0.f;
      #pragma unroll
      for (int fn = 0; fn < 4; fn++) {
        float v = fmaxf(acc[fm][fn][r] + b1v[fn], 0.f);
        s0 += v * w2a[fn]; s1 += v * w2b[fn];
      }
      #pragma unroll
      for (int mk = 1; mk < 16; mk <<= 1) {
        s0 += __shfl_xor(s0, mk);
        s1 += __shfl_xor(s1, mk);
      }
      size_t mo = (size_t)(mm0 + m);
      if (lr == 0) {
        out[OFF_IH + mo * 2]     = s0 + b2a;
        out[OFF_IH + mo * 2 + 1] = s1 + b2bv;
      }
      if (lr < 2) out[OFF_MC + mo * 2 + lr] = acc[fm][4][r] + bm;
    }
  }
}

// ---------------------------------------------------------------------------
// hic path from hbar (pooling factorizes). 16x16 (a,b) tiles over the [10,90)
// crop; pair-from-hbar -> MFMA (K=512,N=128) -> 3-col head (VALU).
// ---------------------------------------------------------------------------
__device__ __forceinline__ bf16x4 pair4(float4 a, float4 b) {
  bf16x4 r;
  r[0] = (bf16)((a.x + b.x) * 0.5f + a.x * b.x * PAIR_S);
  r[1] = (bf16)((a.y + b.y) * 0.5f + a.y * b.y * PAIR_S);
  r[2] = (bf16)((a.z + b.z) * 0.5f + a.z * b.z * PAIR_S);
  r[3] = (bf16)((a.w + b.w) * 0.5f + a.w * b.w * PAIR_S);
  return r;
}

__global__ __launch_bounds__(256, 2)
void hic_kernel(const float* __restrict__ hbar, const float* __restrict__ wsf,
                const float* __restrict__ hicb, const float* __restrict__ whic,
                const float* __restrict__ bhic, float* __restrict__ out) {
  __shared__ float ha_lds[16][36];
  __shared__ float hb_lds[16][36];
  __shared__ bf16 pair_lds[256][36];
  __shared__ bf16 bt_lds[128][36];
  const int t = threadIdx.x;
  const int wv = t >> 6, l = t & 63;
  const int lr = l & 15, g = l >> 4;
  const int a0 = 10 + blockIdx.x * 16, b0 = 10 + blockIdx.y * 16;
  const bf16* hwt = (const bf16*)(wsf + WS_HWT);
  f32x4 acc[4][8] = {};
  for (int kt = 0; kt < 16; kt++) {
    const int k0 = kt * 32;
    if (t < 64) {
      int row = t >> 2, c = (t & 3) * 8;
      const float* src = hbar + (size_t)(a0 + row) * HID + k0 + c;
      *(float4*)&ha_lds[row][c]     = *(const float4*)src;
      *(float4*)&ha_lds[row][c + 4] = *(const float4*)(src + 4);
    } else if (t < 128) {
      int tt = t - 64;
      int row = tt >> 2, c = (tt & 3) * 8;
      const float* src = hbar + (size_t)(b0 + row) * HID + k0 + c;
      *(float4*)&hb_lds[row][c]     = *(const float4*)src;
      *(float4*)&hb_lds[row][c + 4] = *(const float4*)(src + 4);
    } else {
      int tt = t - 128;
      #pragma unroll
      for (int rep = 0; rep < 4; rep++) {
        int chunk = tt * 4 + rep;
        int n = chunk >> 2, part = chunk & 3;
        bf16x8 v = *(const bf16x8*)(hwt + (size_t)n * HID + k0 + part * 8);
        *(bf16x4*)&bt_lds[n][part * 8]     = __builtin_shufflevector(v, v, 0, 1, 2, 3);
        *(bf16x4*)&bt_lds[n][part * 8 + 4] = __builtin_shufflevector(v, v, 4, 5, 6, 7);
      }
    }
    __syncthreads();
    {
      int m = t;
      const float* pa = &ha_lds[m >> 4][0];
      const float* pb = &hb_lds[m & 15][0];
      #pragma unroll
      for (int c = 0; c < 4; c++) {
        float4 av0 = *(const float4*)(pa + c * 8);
        float4 av1 = *(const float4*)(pa + c * 8 + 4);
        float4 bv0 = *(const float4*)(pb + c * 8);
        float4 bv1 = *(const float4*)(pb + c * 8 + 4);
        *(bf16x4*)&pair_lds[m][c * 8]     = pair4(av0, bv0);
        *(bf16x4*)&pair_lds[m][c * 8 + 4] = pair4(av1, bv1);
      }
    }
    __syncthreads();
    bf16x8 af[4], bfr[8];
    #pragma unroll
    for (int fm = 0; fm < 4; fm++) {
      int row = wv * 64 + fm * 16 + lr;
      af[fm] = join8(*(const bf16x4*)&pair_lds[row][g * 8],
                     *(const bf16x4*)&pair_lds[row][g * 8 + 4]);
    }
    #pragma unroll
    for (int fn = 0; fn < 8; fn++) {
      int col = fn * 16 + lr;
      bfr[fn] = join8(*(const bf16x4*)&bt_lds[col][g * 8],
                      *(const bf16x4*)&bt_lds[col][g * 8 + 4]);
    }
    #pragma unroll
    for (int fm = 0; fm < 4; fm++)
      #pragma unroll
      for (int fn = 0; fn < 8; fn++)
        acc[fm][fn] = __builtin_amdgcn_mfma_f32_16x16x32_bf16(af[fm], bfr[fn], acc[fm][fn], 0, 0, 0);
    __syncthreads();
  }
  float wh0[8], wh1[8], wh2[8], hbv[8];
  #pragma unroll
  for (int fn = 0; fn < 8; fn++) {
    int n = fn * 16 + lr;
    wh0[fn] = whic[n * 3]; wh1[fn] = whic[n * 3 + 1]; wh2[fn] = whic[n * 3 + 2];
    hbv[fn] = hicb[n];
  }
  float bh0 = bhic[0], bh1 = bhic[1], bh2 = bhic[2];
  #pragma unroll
  for (int fm = 0; fm < 4; fm++) {
    #pragma unroll
    for (int r = 0; r < 4; r++) {
      int m = wv * 64 + fm * 16 + g * 4 + r;
      float s0 = 0.f, s1 = 0.f, s2 = 0.f;
      #pragma unroll
      for (int fn = 0; fn < 8; fn++) {
        float v = acc[fm][fn][r] + hbv[fn];
        s0 += v * wh0[fn]; s1 += v * wh1[fn]; s2 += v * wh2[fn];
      }
      #pragma unroll
      for (int mk = 1; mk < 16; mk <<= 1) {
        s0 += __shfl_xor(s0, mk);
        s1 += __shfl_xor(s1, mk);
        s2 += __shfl_xor(s2, mk);
      }
      if (lr == 0) {
        int aa = a0 + (m >> 4) - 10, bb = b0 + (m & 15) - 10;
        size_t o = (size_t)OFF_HIC + (size_t)(aa * 80 + bb) * 3;
        out[o] = s0 + bh0; out[o + 1] = s1 + bh1; out[o + 2] = s2 + bh2;
      }
    }
  }
}

// ---------------------------------------------------------------------------
extern "C" void kernel_launch(void* const* d_in, const int* in_sizes, int n_in,
                              void* d_out, int out_size, void* d_ws, size_t ws_size,
                              hipStream_t stream) {
  (void)in_sizes; (void)n_in; (void)out_size; (void)ws_size;
  const float* x    = (const float*)d_in[0];
  const float* pw1  = (const float*)d_in[1];
  const float* pb1  = (const float*)d_in[2];
  const float* pw2  = (const float*)d_in[3];
  const float* pb2  = (const float*)d_in[4];
  const float* mw   = (const float*)d_in[5];
  const float* mb   = (const float*)d_in[6];
  const float* hw   = (const float*)d_in[7];
  const float* hb   = (const float*)d_in[8];
  const float* wmc  = (const float*)d_in[9];
  const float* bmc  = (const float*)d_in[10];
  const float* wih1 = (const float*)d_in[11];
  const float* bih1 = (const float*)d_in[12];
  const float* wih2 = (const float*)d_in[13];
  const float* bih2 = (const float*)d_in[14];
  const float* whic = (const float*)d_in[15];
  const float* bhic = (const float*)d_in[16];
  float* out = (float*)d_out;
  float* ws  = (float*)d_ws;

  zero_init<<<250, 256, 0, stream>>>(ws);                          // H1, H
  // gemm1: H1 += x @ p_w1            (relu+b1 applied by gemm2's A-read)
  gemm_ks<<<dim3(8, 8, 8), 256, 0, stream>>>(x, pw1, nullptr, ws, 500, 512, 128, 0, 1.f);
  // gemm2: H += relu(H1 + b1) @ p_w2 (b2 applied by consumers)
  gemm_ks<<<dim3(8, 8, 4), 256, 0, stream>>>(ws, pw2, pb1, ws + WS_H, 500, 512, 128, 1, 1.f);
  post_h<<<251, 256, 0, stream>>>(ws + WS_H, pb2, mw, hw, wih1, wmc, ws);   // also zeros U
  // U += 0.5 * (H + b2) @ micro_w    (mb applied in fused epilogue)
  gemm_ks<<<dim3(8, 2, 8), 256, 0, stream>>>(ws + WS_H, mw, pb2, ws + WS_U, 500, 128, 64, 0, 0.5f);
  fused_micro<<<dim3(500, 2), 512, 0, stream>>>(ws, mb, out);
  heads_direct<<<625, 256, 0, stream>>>(out + OFF_MICRO, ws, bih1, wih2, bmc, bih2, out);
  hic_kernel<<<dim3(5, 5), 256, 0, stream>>>(ws + WS_HBAR, ws, hb, whic, bhic, out);
}